// Round 1
// baseline (695.068 us; speedup 1.0000x reference)
//
#include <hip/hip_runtime.h>
#include <math.h>

#define BATCH   8192
#define SEQLEN  8
#define HDIM    2048
#define NEXP    64
#define TOPK    8
#define RSTRIDE (SEQLEN * HDIM)   // floats between consecutive batch rows (position 0 used)

#define ROWS 64                   // rows per block tile (lane = row)
#define KC   64                   // K-chunk staged in LDS per iteration
#define XSTR (KC + 1)             // 65 (odd) -> conflict-free per-lane b32 column reads
#define NTK_BLOCKS 256            // topk grid (fixed: 256 blocks x 4 waves x 8 rows = 8192)
#define WS_HEAD 128               // floats: [0,64) importance, [64,128) load (ATOMIC fallback)
#define WS_PART (2 * NTK_BLOCKS * NEXP)  // per-block imp/load partials (main path)

__global__ void zero_kernel(float* __restrict__ p, int n) {
    int i = blockIdx.x * blockDim.x + threadIdx.x;
    int stride = gridDim.x * blockDim.x;
    for (; i < n; i += stride) p[i] = 0.f;
}

// Block: rows [rb, rb+64) x 64 experts x K-slice [kb, kb+HDIM/SPLITS).
// Wave wv owns experts [16wv, 16wv+16); lane = row. x per-lane from LDS,
// w via wave-uniform float4 VECTOR loads (L1 broadcast, no SGPR pressure —
// previous version risked a serialized s_load chain: 128 SGPRs of w per k8).
template<int SPLITS, bool ATOMIC>
__global__ __launch_bounds__(256) void gemm_kernel(
    const float* __restrict__ hs, const float* __restrict__ gw,
    float* __restrict__ out_part)
{
    constexpr int KS = HDIM / SPLITS;
    const int tid  = threadIdx.x;
    const int lane = tid & 63;
    const int wv   = __builtin_amdgcn_readfirstlane(tid >> 6);  // force wave-uniform
    const int rt   = blockIdx.x / SPLITS;
    const int ks   = blockIdx.x % SPLITS;
    const int rb   = rt * ROWS;
    const int kb   = ks * KS;
    const int eb   = wv * 16;

    __shared__ float Xs[ROWS * XSTR];

    float acc[16];
    #pragma unroll
    for (int e = 0; e < 16; ++e) acc[e] = 0.f;

    for (int c = 0; c < KS; c += KC) {
        if (c) __syncthreads();
        // stage 64 rows x KC floats, coalesced (16 lanes cover one row's 256 B)
        #pragma unroll
        for (int i = 0; i < (ROWS * KC / 4) / 256; ++i) {   // 4 float4 per thread
            int idx = i * 256 + tid;
            int r   = idx >> 4;          // KC/4 = 16 float4 per row
            int p   = idx & 15;
            float4 v = *(const float4*)(hs + (size_t)(rb + r) * RSTRIDE + kb + c + p * 4);
            float* d = &Xs[r * XSTR + p * 4];
            d[0] = v.x; d[1] = v.y; d[2] = v.z; d[3] = v.w;
        }
        __syncthreads();

        const float* __restrict__ xrow  = &Xs[lane * XSTR];
        const float* __restrict__ wbase = gw + (size_t)eb * HDIM + kb + c;
        #pragma unroll
        for (int k8 = 0; k8 < KC; k8 += 8) {
            float xr[8];
            #pragma unroll
            for (int j = 0; j < 8; ++j) xr[j] = xrow[k8 + j];   // conflict-free b32
            #pragma unroll
            for (int e = 0; e < 16; ++e) {
                // explicit dwordx4 vector loads: uniform addr -> L1 broadcast
                float4 w0 = *(const float4*)(wbase + (size_t)e * HDIM + k8);
                float4 w1 = *(const float4*)(wbase + (size_t)e * HDIM + k8 + 4);
                acc[e] = fmaf(xr[0], w0.x, acc[e]);
                acc[e] = fmaf(xr[1], w0.y, acc[e]);
                acc[e] = fmaf(xr[2], w0.z, acc[e]);
                acc[e] = fmaf(xr[3], w0.w, acc[e]);
                acc[e] = fmaf(xr[4], w1.x, acc[e]);
                acc[e] = fmaf(xr[5], w1.y, acc[e]);
                acc[e] = fmaf(xr[6], w1.z, acc[e]);
                acc[e] = fmaf(xr[7], w1.w, acc[e]);
            }
        }
    }

    if (ATOMIC) {
        float* dst = out_part + (size_t)(rb + lane) * NEXP + eb;
        #pragma unroll
        for (int e = 0; e < 16; ++e) atomicAdd(dst + e, acc[e]);
    } else {
        float4* dst = (float4*)(out_part + ((size_t)ks * BATCH + rb + lane) * NEXP + eb);
        #pragma unroll
        for (int q = 0; q < 4; ++q)
            dst[q] = make_float4(acc[4*q], acc[4*q+1], acc[4*q+2], acc[4*q+3]);
    }
}

// Phase 2: reduce split partials, softmax over 64 experts (lane=expert),
// iterative top-8 with lowest-index tie-break, write idx/weights.
// imp/load: per-wave accumulate -> LDS cross-wave reduce -> ONE plain store
// per block (main path, no atomics; atomics only in ATOMIC fallback).
template<int SPLITS, bool ATOMIC>
__global__ __launch_bounds__(256) void topk_kernel(
    const float* __restrict__ part, float* __restrict__ out,
    float* __restrict__ ws_imp, float* __restrict__ ws_load)
{
    const int tid  = threadIdx.x;
    const int lane = tid & 63;
    const int wv   = __builtin_amdgcn_readfirstlane(tid >> 6);
    const int wave_id = blockIdx.x * 4 + wv;

    float imp_local = 0.f, load_local = 0.f;
    #pragma unroll 1
    for (int rr = 0; rr < 8; ++rr) {
        const int row = wave_id * 8 + rr;
        float lv;
        if (ATOMIC) {
            lv = part[(size_t)row * NEXP + lane];
        } else {
            lv = 0.f;
            #pragma unroll
            for (int s = 0; s < SPLITS; ++s)
                lv += part[(size_t)s * BATCH * NEXP + (size_t)row * NEXP + lane];
        }

        // softmax across 64 lanes
        float m = lv;
        #pragma unroll
        for (int off = 32; off >= 1; off >>= 1) m = fmaxf(m, __shfl_xor(m, off, 64));
        float e = expf(lv - m);
        float s = e;
        #pragma unroll
        for (int off = 32; off >= 1; off >>= 1) s += __shfl_xor(s, off, 64);
        float prob = e / s;
        imp_local += prob;

        // iterative top-8: butterfly argmax, ties -> lowest index
        float v = prob;
        float myv = 0.f; int myi = 0; float wsum = 0.f;
        #pragma unroll 1
        for (int i = 0; i < TOPK; ++i) {
            float bv = v; int bi = lane;
            #pragma unroll
            for (int off = 32; off >= 1; off >>= 1) {
                float ov = __shfl_xor(bv, off, 64);
                int   oi = __shfl_xor(bi, off, 64);
                if (ov > bv || (ov == bv && oi < bi)) { bv = ov; bi = oi; }
            }
            wsum += bv;
            if (lane == i)  { myv = bv; myi = bi; }
            if (lane == bi) { v = -INFINITY; load_local += 1.f; }
        }
        wsum = fmaxf(wsum, 1e-8f);
        if (lane < TOPK) {
            out[(size_t)row * TOPK + lane] = (float)myi;
            out[(size_t)BATCH * TOPK + (size_t)row * TOPK + lane] = myv / wsum;
        }
    }

    // cross-wave reduction in LDS, then one write (or atomic in fallback) per block
    __shared__ float sRed[2][4][64];
    sRed[0][wv][lane] = imp_local;
    sRed[1][wv][lane] = load_local;
    __syncthreads();
    if (wv == 0) {
        float si = sRed[0][0][lane] + sRed[0][1][lane] + sRed[0][2][lane] + sRed[0][3][lane];
        float sl = sRed[1][0][lane] + sRed[1][1][lane] + sRed[1][2][lane] + sRed[1][3][lane];
        if (ATOMIC) {
            atomicAdd(&ws_imp[lane], si);
            atomicAdd(&ws_load[lane], sl);
        } else {
            ws_imp[(size_t)blockIdx.x * NEXP + lane]  = si;   // per-block partial
            ws_load[(size_t)blockIdx.x * NEXP + lane] = sl;
        }
    }
}

template<bool REDUCE>
__global__ void router_aux(const float* __restrict__ ws_imp,
                           const float* __restrict__ ws_load,
                           float* __restrict__ out)
{
    const int lane = threadIdx.x;
    float imp, load;
    if (REDUCE) {
        imp = 0.f; load = 0.f;
        #pragma unroll 4
        for (int b = 0; b < NTK_BLOCKS; ++b) {
            imp  += ws_imp[(size_t)b * NEXP + lane];
            load += ws_load[(size_t)b * NEXP + lane];
        }
    } else {
        imp  = ws_imp[lane];
        load = ws_load[lane];
    }
    float v = (float)NEXP * (imp / (float)BATCH) * (load / (float)(BATCH * TOPK));
    #pragma unroll
    for (int off = 32; off >= 1; off >>= 1) v += __shfl_xor(v, off, 64);
    if (lane == 0) out[2 * BATCH * TOPK] = v;
}

extern "C" void kernel_launch(void* const* d_in, const int* in_sizes, int n_in,
                              void* d_out, int out_size, void* d_ws, size_t ws_size,
                              hipStream_t stream) {
    const float* hs = (const float*)d_in[0];   // [8192, 8, 2048] fp32
    const float* gw = (const float*)d_in[1];   // [64, 2048] fp32
    float* out = (float*)d_out;
    float* wsf = (float*)d_ws;

    float* pimp  = wsf + WS_HEAD;                       // [256][64] per-block importance
    float* pload = pimp + NTK_BLOCKS * NEXP;            // [256][64] per-block load
    float* part  = wsf + WS_HEAD + WS_PART;             // gemm K-split partials

    const size_t need8 = (size_t)(WS_HEAD + WS_PART + 8 * BATCH * NEXP) * sizeof(float); // ~17 MB
    const size_t need4 = (size_t)(WS_HEAD + WS_PART + 4 * BATCH * NEXP) * sizeof(float); // ~8.6 MB

    if (ws_size >= need8) {
        gemm_kernel<8, false><<<(BATCH / ROWS) * 8, 256, 0, stream>>>(hs, gw, part);
        topk_kernel<8, false><<<NTK_BLOCKS, 256, 0, stream>>>(part, out, pimp, pload);
        router_aux<true><<<1, 64, 0, stream>>>(pimp, pload, out);
    } else if (ws_size >= need4) {
        gemm_kernel<4, false><<<(BATCH / ROWS) * 4, 256, 0, stream>>>(hs, gw, part);
        topk_kernel<4, false><<<NTK_BLOCKS, 256, 0, stream>>>(part, out, pimp, pload);
        router_aux<true><<<1, 64, 0, stream>>>(pimp, pload, out);
    } else {
        // atomic fallback: accumulators at wsf[0..128), logits at wsf+WS_HEAD
        zero_kernel<<<512, 256, 0, stream>>>(wsf, WS_HEAD + BATCH * NEXP);
        gemm_kernel<8, true><<<(BATCH / ROWS) * 8, 256, 0, stream>>>(hs, gw, wsf + WS_HEAD);
        topk_kernel<8, true><<<NTK_BLOCKS, 256, 0, stream>>>(wsf + WS_HEAD, out, wsf, wsf + NEXP);
        router_aux<false><<<1, 64, 0, stream>>>(wsf, wsf + NEXP, out);
    }
}